// Round 8
// baseline (503.794 us; speedup 1.0000x reference)
//
#include <hip/hip_runtime.h>
#include <cstddef>

typedef _Float16 f16x8 __attribute__((ext_vector_type(8)));
typedef _Float16 f16x4 __attribute__((ext_vector_type(4)));
typedef float f32x4 __attribute__((ext_vector_type(4)));

// Problem constants
constexpr int BATCH = 128;
constexpr int T     = 16;
constexpr int ROWS  = BATCH * T * T;  // 32768
constexpr int WID   = 100;
constexpr int NB    = 50;
constexpr int KP    = 128;            // padded K (4 MFMA k-steps of 32)
constexpr int NP    = 128;            // padded N (8 col-tiles of 16)
constexpr int RPW   = 32;             // rows per workgroup -> grid 1024 = 4 WG/CU
constexpr int WCH   = 16384;          // f16 elements per fragment-imaged matrix

// ---------------------------------------------------------------------------
// Prep: split weights into f16 hi/lo pairs (w = hi + lo, lo = w - (f16)w) in
// MFMA fragment stream order (A/B images identical on gfx950 16x16x32).
// Chunk (bk,m,kap,tau) is 1KB: lane L, elem i ->
// W[k=32*kap+(L>>4)*8+i][col=16*tau+(L&15)], zero-padded outside 100x100.
// Also colsum of Wa for the b1 scalar-bias fold.
// ---------------------------------------------------------------------------
__global__ __launch_bounds__(256) void prep_kernel(
    const float* __restrict__ Wa, const float* __restrict__ Wb,
    _Float16* __restrict__ whi, _Float16* __restrict__ wlo,
    float* __restrict__ csA) {
  const int bid = blockIdx.x;          // 0..99 = bk*2 + m
  const int bk = bid >> 1, m = bid & 1;
  const float* src = (m ? Wb : Wa) + (size_t)bk * (WID * WID);
  _Float16* dh = whi + (size_t)bid * WCH;
  _Float16* dl = wlo + (size_t)bid * WCH;
  for (int e = threadIdx.x; e < WCH; e += 256) {
    const int i   = e & 7;
    const int L   = (e >> 3) & 63;
    const int tau = (e >> 9) & 7;
    const int kap = e >> 12;
    const int k   = 32 * kap + (L >> 4) * 8 + i;
    const int col = 16 * tau + (L & 15);
    const float v = (k < WID && col < WID) ? src[k * WID + col] : 0.0f;
    const _Float16 hi = (_Float16)v;
    dh[e] = hi;
    dl[e] = (_Float16)(v - (float)hi);
  }
  if (!m) {
    for (int col = threadIdx.x; col < NP; col += 256) {
      float s = 0.0f;
      if (col < WID) {
        for (int k = 0; k < WID; ++k) s += src[k * WID + col];
      }
      csA[bk * NP + col] = s;
    }
  }
}

// ---------------------------------------------------------------------------
// First layer: gather 45-wide stencil rows, x0 = relu(flat @ W0)
// ---------------------------------------------------------------------------
__global__ __launch_bounds__(256) void first_layer_kernel(
    const float* __restrict__ inp, const float* __restrict__ W0,
    float* __restrict__ x0) {
  __shared__ float w0s[45 * WID];
  for (int i = threadIdx.x; i < 45 * WID; i += 256) w0s[i] = W0[i];
  __syncthreads();

  const int rq  = threadIdx.x >> 2;
  const int cq  = threadIdx.x & 3;
  const int row = blockIdx.x * 64 + rq;
  const int b   = row >> 8;
  const int t1  = (row >> 4) & 15;
  const int t2  = row & 15;
  const int g1  = 2 * t1, g2 = 2 * t2;
  const int g1m = (g1 + 31) & 31, g2m = (g2 + 31) & 31;
  const float* base = inp + (size_t)b * (32 * 32 * 9);
  const float* p0 = base + ((g1 + 1) * 32 + g2) * 9;
  const float* p1 = base + (g1m * 32 + g2) * 9;
  const float* p2 = base + (g1 * 32 + (g2 + 1)) * 9;
  const float* p3 = base + (g1 * 32 + g2m) * 9;
  const float* p4 = base + (g1 * 32 + g2) * 9;

  float f[45];
#pragma unroll
  for (int qq = 0; qq < 9; ++qq) {
    f[qq]      = p0[qq];
    f[9 + qq]  = p1[qq];
    f[18 + qq] = p2[qq];
    f[27 + qq] = p3[qq];
    f[36 + qq] = p4[qq];
  }

  float acc[25];
#pragma unroll
  for (int j = 0; j < 25; ++j) acc[j] = 0.0f;
  const int j0 = cq * 25;
#pragma unroll
  for (int k = 0; k < 45; ++k) {
    const float fv = f[k];
#pragma unroll
    for (int j = 0; j < 25; ++j) acc[j] += fv * w0s[k * WID + j0 + j];
  }
  float* orow = x0 + (size_t)row * WID + j0;
#pragma unroll
  for (int j = 0; j < 25; ++j) orow[j] = fmaxf(acc[j], 0.0f);
}

// ---------------------------------------------------------------------------
// Chain: 50 residual blocks, split-f16 MFMA (f32 accum, error ~2^-22).
// 1024 WGs x 256 thr (4 waves), 32 rows/WG -> 4 WG/CU.
// Operand swap: mfma(A=w_frag, B=x_frag) -> C: col=x-row, regs=4 consecutive j
// => epilogue writes are ds_write_b64 (f16x4 hi/lo), x0 access is float4.
// LDS: x hi/lo f16 [32][128] XOR-swizzled (k ^ ((row&7)<<3)); v overwrites x
// in place (fp32 residual x in registers). Weights global->VGPR direct.
// Per GEMM per wave: 16 B-loads(global b128), 16 A-reads(ds b128), 48 MFMA.
// ---------------------------------------------------------------------------
__global__ __launch_bounds__(256, 2) void chain_kernel(
    float* __restrict__ x0,
    const _Float16* __restrict__ whi, const _Float16* __restrict__ wlo,
    const float* __restrict__ csA,
    const float* __restrict__ B1, const float* __restrict__ B2,
    const float* __restrict__ B3, const float* __restrict__ B4,
    const float* __restrict__ M) {
  __shared__ __align__(16) _Float16 xhs[RPW * KP];   // 8 KB
  __shared__ __align__(16) _Float16 xls[RPW * KP];   // 8 KB

  const int tid  = threadIdx.x;
  const int lane = tid & 63;
  const int uw   = __builtin_amdgcn_readfirstlane(tid >> 6);  // wave 0..3
  const int q    = lane >> 4;   // 0..3
  const int fr   = lane & 15;   // 0..15  (= x-row within row-tile)
  const int rbase = blockIdx.x * RPW;

  // fill x hi/lo (f32 -> split f16, swizzled); pad k>=100 zeroed
  for (int i = tid; i < RPW * KP; i += 256) {
    const int row = i >> 7, k = i & 127;
    const float v = (k < WID) ? x0[(size_t)(rbase + row) * WID + k] : 0.0f;
    const _Float16 hi = (_Float16)v;
    const int a = row * KP + (k ^ ((row & 7) << 3));
    xhs[a] = hi;
    xls[a] = (_Float16)(v - (float)hi);
  }

  // per-thread output coordinates: j = j0c[c] + reg (4 consecutive), row = 16*nt + fr
  int j0c[2];
#pragma unroll
  for (int c = 0; c < 2; ++c) j0c[c] = 16 * (2 * uw + c) + 4 * q;

  // fp32 residual state: [nt][c] = float4 over 4 consecutive j
  f32x4 xres[2][2];
#pragma unroll
  for (int nt = 0; nt < 2; ++nt)
#pragma unroll
    for (int c = 0; c < 2; ++c) {
      const int row = 16 * nt + fr;
      if (j0c[c] < WID) {
        xres[nt][c] = *(const f32x4*)&x0[(size_t)(rbase + row) * WID + j0c[c]];
      } else {
        xres[nt][c] = (f32x4){0.f, 0.f, 0.f, 0.f};
      }
    }
  __syncthreads();

  f32x4 acc[2][2];
  auto zero_acc = [&]() {
#pragma unroll
    for (int nt = 0; nt < 2; ++nt)
#pragma unroll
      for (int c = 0; c < 2; ++c) acc[nt][c] = (f32x4){0.f, 0.f, 0.f, 0.f};
  };

  // split-f16 GEMM: acc += (wh+wl)^T-image @ (xh+xl), dropping wl*xl (~2^-22)
  auto kloop = [&](const _Float16* __restrict__ gh,
                   const _Float16* __restrict__ gl) {
    f16x8 wh[4][2], wl[4][2];
#pragma unroll
    for (int kap = 0; kap < 4; ++kap)
#pragma unroll
      for (int c = 0; c < 2; ++c) {
        const int off = (kap * 8 + 2 * uw + c) * 512 + lane * 8;
        wh[kap][c] = *(const f16x8*)&gh[off];
        wl[kap][c] = *(const f16x8*)&gl[off];
      }
#pragma unroll
    for (int kap = 0; kap < 4; ++kap) {
      f16x8 xh_[2], xl_[2];
#pragma unroll
      for (int nt = 0; nt < 2; ++nt) {
        const int row = 16 * nt + fr;
        const int off = row * KP + ((32 * kap + 8 * q) ^ ((fr & 7) << 3));
        xh_[nt] = *(const f16x8*)&xhs[off];
        xl_[nt] = *(const f16x8*)&xls[off];
      }
#pragma unroll
      for (int nt = 0; nt < 2; ++nt)
#pragma unroll
        for (int c = 0; c < 2; ++c) {
          acc[nt][c] = __builtin_amdgcn_mfma_f32_16x16x32_f16(
              wh[kap][c], xh_[nt], acc[nt][c], 0, 0, 0);
          acc[nt][c] = __builtin_amdgcn_mfma_f32_16x16x32_f16(
              wl[kap][c], xh_[nt], acc[nt][c], 0, 0, 0);
          acc[nt][c] = __builtin_amdgcn_mfma_f32_16x16x32_f16(
              wh[kap][c], xl_[nt], acc[nt][c], 0, 0, 0);
        }
    }
  };

  for (int bk = 0; bk < NB; ++bk) {
    // ---------------- GEMM1: v = 2*relu(2*((x+b1)@Wa) + b2) + b3 ----------
    zero_acc();
    kloop(whi + (size_t)(bk * 2) * WCH, wlo + (size_t)(bk * 2) * WCH);
    __syncthreads();            // all x reads done; xs reusable
    {
      const float b1 = B1[bk], b2 = B2[bk], b3 = B3[bk];
#pragma unroll
      for (int c = 0; c < 2; ++c) {
        if (j0c[c] < WID) {
          const f32x4 cs = *(const f32x4*)&csA[bk * NP + j0c[c]];
#pragma unroll
          for (int nt = 0; nt < 2; ++nt) {
            const int row = 16 * nt + fr;
            f16x4 hv, lv;
#pragma unroll
            for (int r = 0; r < 4; ++r) {
              const float t = 2.0f * (acc[nt][c][r] + b1 * cs[r]) + b2;
              const float v = 2.0f * fmaxf(t, 0.0f) + b3;
              const _Float16 hi = (_Float16)v;
              hv[r] = hi;
              lv[r] = (_Float16)(v - (float)hi);
            }
            const int a = row * KP + (j0c[c] ^ ((row & 7) << 3));
            *(f16x4*)&xhs[a] = hv;
            *(f16x4*)&xls[a] = lv;
          }
        }
      }
    }
    __syncthreads();            // publish v

    // ---------------- GEMM2: x = relu(x + (v@Wb)*m + b4) -------------------
    zero_acc();
    kloop(whi + (size_t)(bk * 2 + 1) * WCH, wlo + (size_t)(bk * 2 + 1) * WCH);
    __syncthreads();            // all v reads done; xs reusable
    {
      const float b4v = B4[bk], mm = M[bk];
#pragma unroll
      for (int c = 0; c < 2; ++c) {
        if (j0c[c] < WID) {
#pragma unroll
          for (int nt = 0; nt < 2; ++nt) {
            const int row = 16 * nt + fr;
            f16x4 hv, lv;
#pragma unroll
            for (int r = 0; r < 4; ++r) {
              const float xn = fmaxf(xres[nt][c][r] + acc[nt][c][r] * mm + b4v, 0.0f);
              xres[nt][c][r] = xn;
              const _Float16 hi = (_Float16)xn;
              hv[r] = hi;
              lv[r] = (_Float16)(xn - (float)hi);
            }
            const int a = row * KP + (j0c[c] ^ ((row & 7) << 3));
            *(f16x4*)&xhs[a] = hv;
            *(f16x4*)&xls[a] = lv;
          }
        }
      }
    }
    __syncthreads();            // publish x(bk+1)
  }

  // write back fp32 residual state (float4 per (nt,c))
#pragma unroll
  for (int nt = 0; nt < 2; ++nt)
#pragma unroll
    for (int c = 0; c < 2; ++c) {
      const int row = 16 * nt + fr;
      if (j0c[c] < WID)
        *(f32x4*)&x0[(size_t)(rbase + row) * WID + j0c[c]] = xres[nt][c];
    }
}

// ---------------------------------------------------------------------------
// Output head + stencil epilogue. One block per batch image (16x16 grid).
// ---------------------------------------------------------------------------
__global__ __launch_bounds__(256) void out_kernel(
    const float* __restrict__ inp, const float* __restrict__ x0,
    const float* __restrict__ Wout, const float* __restrict__ bout,
    float* __restrict__ out) {
  __shared__ float ys[256 * 4];
  __shared__ float wouts[WID * 4];
  __shared__ float bos[4];
  const int tid = threadIdx.x;
  const int b   = blockIdx.x;

  for (int i = tid; i < WID * 4; i += 256) wouts[i] = Wout[i];
  if (tid < 4) bos[tid] = bout[tid];
  __syncthreads();

  const int row = b * 256 + tid;
  const float* xr = x0 + (size_t)row * WID;
  float a0 = 0.f, a1 = 0.f, a2 = 0.f, a3 = 0.f;
#pragma unroll 4
  for (int k = 0; k < WID; ++k) {
    const float xv = xr[k];
    a0 += xv * wouts[k * 4 + 0];
    a1 += xv * wouts[k * 4 + 1];
    a2 += xv * wouts[k * 4 + 2];
    a3 += xv * wouts[k * 4 + 3];
  }
  ys[tid * 4 + 0] = a0 + bos[0];
  ys[tid * 4 + 1] = a1 + bos[1];
  ys[tid * 4 + 2] = a2 + bos[2];
  ys[tid * 4 + 3] = a3 + bos[3];
  __syncthreads();

  const int i = tid >> 4, j = tid & 15;
  const int ip1 = (i + 1) & 15, im1 = (i + 15) & 15;
  const int jp1 = (j + 1) & 15, jm1 = (j + 15) & 15;
  auto Y = [&](int a, int c, int comp) { return ys[(((a << 4) | c) << 2) + comp]; };
  const float y0 = Y(i, j, 0), y1 = Y(i, j, 1), y2 = Y(i, j, 2), y3 = Y(i, j, 3);
  const float right_c = y0 / (Y(ip1, j, 1) + y0);
  const float left_c  = y1 / (y1 + Y(im1, j, 0));
  const float up_c    = y2 / (y2 + Y(i, jp1, 3));
  const float down_c  = y3 / (Y(i, jm1, 2) + y3);

  const float* base = inp + (size_t)b * (32 * 32 * 9);
  const int g1 = 2 * i + 1, g1m = (2 * i + 31) & 31;
  const int g2 = 2 * j + 1, g2m = (2 * j + 31) & 31;
  const float* oo = base + (g1 * 32 + g2) * 9;
  const float* oi = base + (g1 * 32 + g2m) * 9;
  const float* io = base + (g1m * 32 + g2) * 9;
  const float* ii = base + (g1m * 32 + g2m) * 9;
  const float ru = -(oo[0] + oo[3] * right_c + oo[1] * up_c) / oo[4];
  const float rd = -(oi[2] + oi[5] * right_c + oi[1] * down_c) / oi[4];
  const float lu = -(io[6] + io[3] * left_c + io[7] * up_c) / io[4];
  const float ld = -(ii[8] + ii[5] * left_c + ii[7] * down_c) / ii[4];

  float* o = out + (size_t)row * 9;
  o[0] = ld;     o[1] = left_c;  o[2] = lu;
  o[3] = down_c; o[4] = 1.0f;    o[5] = up_c;
  o[6] = rd;     o[7] = right_c; o[8] = ru;
}

// ---------------------------------------------------------------------------
extern "C" void kernel_launch(void* const* d_in, const int* in_sizes, int n_in,
                              void* d_out, int out_size, void* d_ws, size_t ws_size,
                              hipStream_t stream) {
  const float* inp  = (const float*)d_in[0];
  const float* W0   = (const float*)d_in[1];
  const float* Wa   = (const float*)d_in[2];
  const float* Wb   = (const float*)d_in[3];
  const float* B1   = (const float*)d_in[4];
  const float* B2   = (const float*)d_in[5];
  const float* B3   = (const float*)d_in[6];
  const float* B4   = (const float*)d_in[7];
  const float* M    = (const float*)d_in[8];
  const float* Wout = (const float*)d_in[9];
  const float* bout = (const float*)d_in[10];
  float* out = (float*)d_out;

  float* ws       = (float*)d_ws;
  float* x0       = ws;                            // 3,276,800 f32
  _Float16* whi   = (_Float16*)(ws + 3276800);     // 100*16384 f16 (819,200 f32)
  _Float16* wlo   = (_Float16*)(ws + 3276800 + 819200);
  float* csA      = ws + 3276800 + 819200 + 819200; // 50*128 f32

  hipLaunchKernelGGL(prep_kernel, dim3(100), dim3(256), 0, stream,
                     Wa, Wb, whi, wlo, csA);
  hipLaunchKernelGGL(first_layer_kernel, dim3(ROWS / 64), dim3(256), 0, stream,
                     inp, W0, x0);
  hipLaunchKernelGGL(chain_kernel, dim3(ROWS / RPW), dim3(256), 0, stream,
                     x0, whi, wlo, csA, B1, B2, B3, B4, M);
  hipLaunchKernelGGL(out_kernel, dim3(BATCH), dim3(256), 0, stream,
                     inp, x0, Wout, bout, out);
}

// Round 9
// 337.150 us; speedup vs baseline: 1.4943x; 1.4943x over previous
//
#include <hip/hip_runtime.h>
#include <cstddef>

typedef _Float16 f16x8 __attribute__((ext_vector_type(8)));
typedef _Float16 f16x4 __attribute__((ext_vector_type(4)));
typedef float f32x4 __attribute__((ext_vector_type(4)));
typedef float f32x16 __attribute__((ext_vector_type(16)));

// Problem constants
constexpr int BATCH = 128;
constexpr int T     = 16;
constexpr int ROWS  = BATCH * T * T;  // 32768
constexpr int WID   = 100;
constexpr int NB    = 50;
constexpr int KP    = 128;            // LDS k-stride (pow2 for swizzle)
constexpr int KS    = 7;              // k-steps of 16 -> K=112 >= 100
constexpr int NP    = 128;            // padded N (4 col-tiles of 32)
constexpr int RPW   = 64;             // rows per workgroup
constexpr int WCH   = KS * 4 * 512;   // 14336 f16 per fragment-imaged matrix

// ---------------------------------------------------------------------------
// Prep: split weights into f16 hi/lo in 32x32x16 A-fragment stream order.
// Chunk (bk*2+m, ks, ct) is 1KB: lane L, elem i ->
//   W[k = 16*ks + 8*(L>>5) + i][j = 32*ct + (L&31)], zero-padded.
// Also colsum of Wa (128 cols) for the b1 scalar-bias fold.
// ---------------------------------------------------------------------------
__global__ __launch_bounds__(256) void prep_kernel(
    const float* __restrict__ Wa, const float* __restrict__ Wb,
    _Float16* __restrict__ whi, _Float16* __restrict__ wlo,
    float* __restrict__ csA) {
  const int bid = blockIdx.x;          // 0..99 = bk*2 + m
  const int bk = bid >> 1, m = bid & 1;
  const float* src = (m ? Wb : Wa) + (size_t)bk * (WID * WID);
  _Float16* dh = whi + (size_t)bid * WCH;
  _Float16* dl = wlo + (size_t)bid * WCH;
  for (int e = threadIdx.x; e < WCH; e += 256) {
    const int i  = e & 7;
    const int L  = (e >> 3) & 63;
    const int ct = (e >> 9) & 3;
    const int ks = e >> 11;
    const int k  = 16 * ks + 8 * (L >> 5) + i;
    const int j  = 32 * ct + (L & 31);
    const float v = (k < WID && j < WID) ? src[k * WID + j] : 0.0f;
    const _Float16 hi = (_Float16)v;
    dh[e] = hi;
    dl[e] = (_Float16)(v - (float)hi);
  }
  if (!m) {
    for (int col = threadIdx.x; col < NP; col += 256) {
      float s = 0.0f;
      if (col < WID) {
        for (int k = 0; k < WID; ++k) s += src[k * WID + col];
      }
      csA[bk * NP + col] = s;
    }
  }
}

// ---------------------------------------------------------------------------
// First layer: gather 45-wide stencil rows, x0 = relu(flat @ W0)
// ---------------------------------------------------------------------------
__global__ __launch_bounds__(256) void first_layer_kernel(
    const float* __restrict__ inp, const float* __restrict__ W0,
    float* __restrict__ x0) {
  __shared__ float w0s[45 * WID];
  for (int i = threadIdx.x; i < 45 * WID; i += 256) w0s[i] = W0[i];
  __syncthreads();

  const int rq  = threadIdx.x >> 2;
  const int cq  = threadIdx.x & 3;
  const int row = blockIdx.x * 64 + rq;
  const int b   = row >> 8;
  const int t1  = (row >> 4) & 15;
  const int t2  = row & 15;
  const int g1  = 2 * t1, g2 = 2 * t2;
  const int g1m = (g1 + 31) & 31, g2m = (g2 + 31) & 31;
  const float* base = inp + (size_t)b * (32 * 32 * 9);
  const float* p0 = base + ((g1 + 1) * 32 + g2) * 9;
  const float* p1 = base + (g1m * 32 + g2) * 9;
  const float* p2 = base + (g1 * 32 + (g2 + 1)) * 9;
  const float* p3 = base + (g1 * 32 + g2m) * 9;
  const float* p4 = base + (g1 * 32 + g2) * 9;

  float f[45];
#pragma unroll
  for (int qq = 0; qq < 9; ++qq) {
    f[qq]      = p0[qq];
    f[9 + qq]  = p1[qq];
    f[18 + qq] = p2[qq];
    f[27 + qq] = p3[qq];
    f[36 + qq] = p4[qq];
  }

  float acc[25];
#pragma unroll
  for (int j = 0; j < 25; ++j) acc[j] = 0.0f;
  const int j0 = cq * 25;
#pragma unroll
  for (int k = 0; k < 45; ++k) {
    const float fv = f[k];
#pragma unroll
    for (int j = 0; j < 25; ++j) acc[j] += fv * w0s[k * WID + j0 + j];
  }
  float* orow = x0 + (size_t)row * WID + j0;
#pragma unroll
  for (int j = 0; j < 25; ++j) orow[j] = fmaxf(acc[j], 0.0f);
}

// ---------------------------------------------------------------------------
// Chain: 50 residual blocks, split-f16 MFMA 32x32x16 (f32 accum, ~2^-22).
// 512 WGs x 512 thr (8 waves) -> 2 WG/CU, 16 waves/CU.
// Wave (rt,ct) owns rows [32rt,32rt+32) x cols [32ct,32ct+32); acc = f32x16.
// LDS: x hi/lo f16 [64][128] XOR-swizzled (k ^ 8*(row&7)); v overwrites x in
// place (fp32 residual in regs). Weights global->VGPR, streamed per k-step.
// Per GEMM per wave: 14 w-loads(global b128), 14 A-reads(ds b128), 21 MFMA.
// ---------------------------------------------------------------------------
__global__ __launch_bounds__(512, 2) void chain_kernel(
    float* __restrict__ x0,
    const _Float16* __restrict__ whi, const _Float16* __restrict__ wlo,
    const float* __restrict__ csA,
    const float* __restrict__ B1, const float* __restrict__ B2,
    const float* __restrict__ B3, const float* __restrict__ B4,
    const float* __restrict__ M) {
  __shared__ __align__(16) _Float16 xhs[RPW * KP];   // 16 KB
  __shared__ __align__(16) _Float16 xls[RPW * KP];   // 16 KB

  const int tid  = threadIdx.x;
  const int lane = tid & 63;
  const int uw   = __builtin_amdgcn_readfirstlane(tid >> 6);  // wave 0..7
  const int rt   = uw >> 2;     // row-tile 0..1
  const int ct   = uw & 3;      // col-tile 0..3
  const int jr   = lane & 31;   // x-row within tile / w-col lane
  const int kg   = lane >> 5;   // k-group 0..1
  const int rbase = blockIdx.x * RPW;

  const int row_x = 32 * rt + jr;            // this lane's x-row
  const int sw    = (row_x & 7) << 3;        // XOR swizzle (f16 units)

  // fill x hi/lo (f32 -> split f16, swizzled); k >= 100 zeroed
  for (int i = tid; i < RPW * KP; i += 512) {
    const int row = i >> 7, k = i & 127;
    const float v = (k < WID) ? x0[(size_t)(rbase + row) * WID + k] : 0.0f;
    const _Float16 hi = (_Float16)v;
    const int a = row * KP + (k ^ ((row & 7) << 3));
    xhs[a] = hi;
    xls[a] = (_Float16)(v - (float)hi);
  }

  // output j coordinates: j = j0g[g] + r, 4 groups of 4 consecutive
  int j0g[4];
#pragma unroll
  for (int g = 0; g < 4; ++g) j0g[g] = 32 * ct + 4 * kg + 8 * g;

  // fp32 residual state: 4 x f32x4 (row fixed = row_x)
  f32x4 xres[4];
#pragma unroll
  for (int g = 0; g < 4; ++g) {
    if (j0g[g] <= WID - 4) {
      xres[g] = *(const f32x4*)&x0[(size_t)(rbase + row_x) * WID + j0g[g]];
    } else {
      xres[g] = (f32x4){0.f, 0.f, 0.f, 0.f};
    }
  }
  __syncthreads();

  f32x16 acc;

  // split-f16 GEMM tile: acc += (wh+wl)^T @ (xh+xl), dropping wl*xl
  auto kloop = [&](const int gidx) {
    const _Float16* gh = whi + (size_t)gidx * WCH + ct * 512;
    const _Float16* gl = wlo + (size_t)gidx * WCH + ct * 512;
#pragma unroll
    for (int ks = 0; ks < KS; ++ks) {
      const f16x8 wh = *(const f16x8*)&gh[ks * 2048 + lane * 8];
      const f16x8 wl = *(const f16x8*)&gl[ks * 2048 + lane * 8];
      const int off = row_x * KP + ((16 * ks + 8 * kg) ^ sw);
      const f16x8 xh = *(const f16x8*)&xhs[off];
      const f16x8 xl = *(const f16x8*)&xls[off];
      acc = __builtin_amdgcn_mfma_f32_32x32x16_f16(wh, xh, acc, 0, 0, 0);
      acc = __builtin_amdgcn_mfma_f32_32x32x16_f16(wl, xh, acc, 0, 0, 0);
      acc = __builtin_amdgcn_mfma_f32_32x32x16_f16(wh, xl, acc, 0, 0, 0);
    }
  };

  for (int bk = 0; bk < NB; ++bk) {
    // ---------------- GEMM1: v = 2*relu(2*((x+b1)@Wa) + b2) + b3 ----------
#pragma unroll
    for (int e = 0; e < 16; ++e) acc[e] = 0.0f;
    kloop(bk * 2);
    __syncthreads();            // all x reads done; xs reusable
    {
      const float b1 = B1[bk], b2 = B2[bk], b3 = B3[bk];
#pragma unroll
      for (int g = 0; g < 4; ++g) {
        const f32x4 cs = *(const f32x4*)&csA[bk * NP + j0g[g]];
        f16x4 hv, lv;
#pragma unroll
        for (int r = 0; r < 4; ++r) {
          const float t = 2.0f * (acc[g * 4 + r] + b1 * cs[r]) + b2;
          const float v = 2.0f * fmaxf(t, 0.0f) + b3;
          const _Float16 hi = (_Float16)v;
          hv[r] = hi;
          lv[r] = (_Float16)(v - (float)hi);
        }
        const int a = row_x * KP + (j0g[g] ^ sw);
        *(f16x4*)&xhs[a] = hv;
        *(f16x4*)&xls[a] = lv;
      }
    }
    __syncthreads();            // publish v

    // ---------------- GEMM2: x = relu(x + (v@Wb)*m + b4) -------------------
#pragma unroll
    for (int e = 0; e < 16; ++e) acc[e] = 0.0f;
    kloop(bk * 2 + 1);
    __syncthreads();            // all v reads done; xs reusable
    {
      const float b4v = B4[bk], mm = M[bk];
#pragma unroll
      for (int g = 0; g < 4; ++g) {
        f16x4 hv, lv;
#pragma unroll
        for (int r = 0; r < 4; ++r) {
          const float xn = fmaxf(xres[g][r] + acc[g * 4 + r] * mm + b4v, 0.0f);
          xres[g][r] = xn;
          const _Float16 hi = (_Float16)xn;
          hv[r] = hi;
          lv[r] = (_Float16)(xn - (float)hi);
        }
        const int a = row_x * KP + (j0g[g] ^ sw);
        *(f16x4*)&xhs[a] = hv;
        *(f16x4*)&xls[a] = lv;
      }
    }
    __syncthreads();            // publish x(bk+1)
  }

  // write back fp32 residual state
#pragma unroll
  for (int g = 0; g < 4; ++g) {
    if (j0g[g] <= WID - 4)
      *(f32x4*)&x0[(size_t)(rbase + row_x) * WID + j0g[g]] = xres[g];
  }
}

// ---------------------------------------------------------------------------
// Output head + stencil epilogue. One block per batch image (16x16 grid).
// ---------------------------------------------------------------------------
__global__ __launch_bounds__(256) void out_kernel(
    const float* __restrict__ inp, const float* __restrict__ x0,
    const float* __restrict__ Wout, const float* __restrict__ bout,
    float* __restrict__ out) {
  __shared__ float ys[256 * 4];
  __shared__ float wouts[WID * 4];
  __shared__ float bos[4];
  const int tid = threadIdx.x;
  const int b   = blockIdx.x;

  for (int i = tid; i < WID * 4; i += 256) wouts[i] = Wout[i];
  if (tid < 4) bos[tid] = bout[tid];
  __syncthreads();

  const int row = b * 256 + tid;
  const float* xr = x0 + (size_t)row * WID;
  float a0 = 0.f, a1 = 0.f, a2 = 0.f, a3 = 0.f;
#pragma unroll 4
  for (int k = 0; k < WID; ++k) {
    const float xv = xr[k];
    a0 += xv * wouts[k * 4 + 0];
    a1 += xv * wouts[k * 4 + 1];
    a2 += xv * wouts[k * 4 + 2];
    a3 += xv * wouts[k * 4 + 3];
  }
  ys[tid * 4 + 0] = a0 + bos[0];
  ys[tid * 4 + 1] = a1 + bos[1];
  ys[tid * 4 + 2] = a2 + bos[2];
  ys[tid * 4 + 3] = a3 + bos[3];
  __syncthreads();

  const int i = tid >> 4, j = tid & 15;
  const int ip1 = (i + 1) & 15, im1 = (i + 15) & 15;
  const int jp1 = (j + 1) & 15, jm1 = (j + 15) & 15;
  auto Y = [&](int a, int c, int comp) { return ys[(((a << 4) | c) << 2) + comp]; };
  const float y0 = Y(i, j, 0), y1 = Y(i, j, 1), y2 = Y(i, j, 2), y3 = Y(i, j, 3);
  const float right_c = y0 / (Y(ip1, j, 1) + y0);
  const float left_c  = y1 / (y1 + Y(im1, j, 0));
  const float up_c    = y2 / (y2 + Y(i, jp1, 3));
  const float down_c  = y3 / (Y(i, jm1, 2) + y3);

  const float* base = inp + (size_t)b * (32 * 32 * 9);
  const int g1 = 2 * i + 1, g1m = (2 * i + 31) & 31;
  const int g2 = 2 * j + 1, g2m = (2 * j + 31) & 31;
  const float* oo = base + (g1 * 32 + g2) * 9;
  const float* oi = base + (g1 * 32 + g2m) * 9;
  const float* io = base + (g1m * 32 + g2) * 9;
  const float* ii = base + (g1m * 32 + g2m) * 9;
  const float ru = -(oo[0] + oo[3] * right_c + oo[1] * up_c) / oo[4];
  const float rd = -(oi[2] + oi[5] * right_c + oi[1] * down_c) / oi[4];
  const float lu = -(io[6] + io[3] * left_c + io[7] * up_c) / io[4];
  const float ld = -(ii[8] + ii[5] * left_c + ii[7] * down_c) / ii[4];

  float* o = out + (size_t)row * 9;
  o[0] = ld;     o[1] = left_c;  o[2] = lu;
  o[3] = down_c; o[4] = 1.0f;    o[5] = up_c;
  o[6] = rd;     o[7] = right_c; o[8] = ru;
}

// ---------------------------------------------------------------------------
extern "C" void kernel_launch(void* const* d_in, const int* in_sizes, int n_in,
                              void* d_out, int out_size, void* d_ws, size_t ws_size,
                              hipStream_t stream) {
  const float* inp  = (const float*)d_in[0];
  const float* W0   = (const float*)d_in[1];
  const float* Wa   = (const float*)d_in[2];
  const float* Wb   = (const float*)d_in[3];
  const float* B1   = (const float*)d_in[4];
  const float* B2   = (const float*)d_in[5];
  const float* B3   = (const float*)d_in[6];
  const float* B4   = (const float*)d_in[7];
  const float* M    = (const float*)d_in[8];
  const float* Wout = (const float*)d_in[9];
  const float* bout = (const float*)d_in[10];
  float* out = (float*)d_out;

  float* ws     = (float*)d_ws;
  float* x0     = ws;                              // 3,276,800 f32
  _Float16* whi = (_Float16*)(ws + 3276800);       // 100*14336 f16 = 716,800 f32
  _Float16* wlo = (_Float16*)(ws + 3276800 + 716800);
  float* csA    = ws + 3276800 + 716800 + 716800;  // 50*128 f32

  hipLaunchKernelGGL(prep_kernel, dim3(100), dim3(256), 0, stream,
                     Wa, Wb, whi, wlo, csA);
  hipLaunchKernelGGL(first_layer_kernel, dim3(ROWS / 64), dim3(256), 0, stream,
                     inp, W0, x0);
  hipLaunchKernelGGL(chain_kernel, dim3(ROWS / RPW), dim3(512), 0, stream,
                     x0, whi, wlo, csA, B1, B2, B3, B4, M);
  hipLaunchKernelGGL(out_kernel, dim3(BATCH), dim3(256), 0, stream,
                     inp, x0, Wout, bout, out);
}

// Round 10
// 328.332 us; speedup vs baseline: 1.5344x; 1.0269x over previous
//
#include <hip/hip_runtime.h>
#include <cstddef>

typedef _Float16 f16x8 __attribute__((ext_vector_type(8)));
typedef _Float16 f16x4 __attribute__((ext_vector_type(4)));
typedef float f32x4 __attribute__((ext_vector_type(4)));
typedef float f32x16 __attribute__((ext_vector_type(16)));

// Problem constants
constexpr int BATCH = 128;
constexpr int T     = 16;
constexpr int ROWS  = BATCH * T * T;  // 32768
constexpr int WID   = 100;
constexpr int NB    = 50;
constexpr int KP    = 128;            // LDS k-stride (pow2 for swizzle)
constexpr int KS    = 7;              // k-steps of 16 -> K=112 >= 100
constexpr int NP    = 128;            // padded N (4 col-tiles of 32)
constexpr int RPW   = 64;             // rows per workgroup
constexpr int WCH   = KS * 4 * 512;   // 14336 f16 per fragment-imaged matrix

// ---------------------------------------------------------------------------
// Prep: split weights into f16 hi/lo in 32x32x16 A-fragment stream order.
// Chunk (bk*2+m, ks, ct) is 1KB: lane L, elem i ->
//   W[k = 16*ks + 8*(L>>5) + i][j = 32*ct + (L&31)], zero-padded.
// Also colsum of Wa (128 cols) for the b1 scalar-bias fold.
// ---------------------------------------------------------------------------
__global__ __launch_bounds__(256) void prep_kernel(
    const float* __restrict__ Wa, const float* __restrict__ Wb,
    _Float16* __restrict__ whi, _Float16* __restrict__ wlo,
    float* __restrict__ csA) {
  const int bid = blockIdx.x;          // 0..99 = bk*2 + m
  const int bk = bid >> 1, m = bid & 1;
  const float* src = (m ? Wb : Wa) + (size_t)bk * (WID * WID);
  _Float16* dh = whi + (size_t)bid * WCH;
  _Float16* dl = wlo + (size_t)bid * WCH;
  for (int e = threadIdx.x; e < WCH; e += 256) {
    const int i  = e & 7;
    const int L  = (e >> 3) & 63;
    const int ct = (e >> 9) & 3;
    const int ks = e >> 11;
    const int k  = 16 * ks + 8 * (L >> 5) + i;
    const int j  = 32 * ct + (L & 31);
    const float v = (k < WID && j < WID) ? src[k * WID + j] : 0.0f;
    const _Float16 hi = (_Float16)v;
    dh[e] = hi;
    dl[e] = (_Float16)(v - (float)hi);
  }
  if (!m) {
    for (int col = threadIdx.x; col < NP; col += 256) {
      float s = 0.0f;
      if (col < WID) {
        for (int k = 0; k < WID; ++k) s += src[k * WID + col];
      }
      csA[bk * NP + col] = s;
    }
  }
}

// ---------------------------------------------------------------------------
// First layer: gather 45-wide stencil rows, x0 = relu(flat @ W0)
// ---------------------------------------------------------------------------
__global__ __launch_bounds__(256) void first_layer_kernel(
    const float* __restrict__ inp, const float* __restrict__ W0,
    float* __restrict__ x0) {
  __shared__ float w0s[45 * WID];
  for (int i = threadIdx.x; i < 45 * WID; i += 256) w0s[i] = W0[i];
  __syncthreads();

  const int rq  = threadIdx.x >> 2;
  const int cq  = threadIdx.x & 3;
  const int row = blockIdx.x * 64 + rq;
  const int b   = row >> 8;
  const int t1  = (row >> 4) & 15;
  const int t2  = row & 15;
  const int g1  = 2 * t1, g2 = 2 * t2;
  const int g1m = (g1 + 31) & 31, g2m = (g2 + 31) & 31;
  const float* base = inp + (size_t)b * (32 * 32 * 9);
  const float* p0 = base + ((g1 + 1) * 32 + g2) * 9;
  const float* p1 = base + (g1m * 32 + g2) * 9;
  const float* p2 = base + (g1 * 32 + (g2 + 1)) * 9;
  const float* p3 = base + (g1 * 32 + g2m) * 9;
  const float* p4 = base + (g1 * 32 + g2) * 9;

  float f[45];
#pragma unroll
  for (int qq = 0; qq < 9; ++qq) {
    f[qq]      = p0[qq];
    f[9 + qq]  = p1[qq];
    f[18 + qq] = p2[qq];
    f[27 + qq] = p3[qq];
    f[36 + qq] = p4[qq];
  }

  float acc[25];
#pragma unroll
  for (int j = 0; j < 25; ++j) acc[j] = 0.0f;
  const int j0 = cq * 25;
#pragma unroll
  for (int k = 0; k < 45; ++k) {
    const float fv = f[k];
#pragma unroll
    for (int j = 0; j < 25; ++j) acc[j] += fv * w0s[k * WID + j0 + j];
  }
  float* orow = x0 + (size_t)row * WID + j0;
#pragma unroll
  for (int j = 0; j < 25; ++j) orow[j] = fmaxf(acc[j], 0.0f);
}

// ---------------------------------------------------------------------------
// Chain: 50 residual blocks, split-f16 MFMA 32x32x16 (f32 accum, ~2^-22).
// 512 WGs x 512 thr (8 waves) -> 2 WG/CU, 16 waves/CU.
// Wave (rt,ct) owns rows [32rt,+32) x cols [32ct,+32); acc = f32x16.
// LDS: x hi/lo AND v hi/lo (separate buffers -> only 2 barriers/block),
// f16 [64][128], XOR-swizzled k ^ ((row&15)<<3) -> 2-way-max bank aliasing.
// Weights global->VGPR, all 14 loads hoisted to kloop top (latency batch).
// fp32 residual x in registers. Per GEMM/wave: 14 gl b128, 14 ds b128, 21 MFMA.
// ---------------------------------------------------------------------------
__global__ __launch_bounds__(512, 2) void chain_kernel(
    float* __restrict__ x0,
    const _Float16* __restrict__ whi, const _Float16* __restrict__ wlo,
    const float* __restrict__ csA,
    const float* __restrict__ B1, const float* __restrict__ B2,
    const float* __restrict__ B3, const float* __restrict__ B4,
    const float* __restrict__ M) {
  __shared__ __align__(16) _Float16 xhs[RPW * KP];   // 16 KB
  __shared__ __align__(16) _Float16 xls[RPW * KP];   // 16 KB
  __shared__ __align__(16) _Float16 vhs[RPW * KP];   // 16 KB
  __shared__ __align__(16) _Float16 vls[RPW * KP];   // 16 KB

  const int tid  = threadIdx.x;
  const int lane = tid & 63;
  const int uw   = __builtin_amdgcn_readfirstlane(tid >> 6);  // wave 0..7
  const int rt   = uw >> 2;     // row-tile 0..1
  const int ct   = uw & 3;      // col-tile 0..3
  const int jr   = lane & 31;   // x-row within tile / w-col lane
  const int kg   = lane >> 5;   // k-group 0..1
  const int rbase = blockIdx.x * RPW;

  const int row_x = 32 * rt + jr;            // this lane's x-row
  const int sw    = (row_x & 15) << 3;       // XOR swizzle (f16 units)

  // fill x hi/lo (f32 -> split f16, swizzled); k >= 100 zeroed
  for (int i = tid; i < RPW * KP; i += 512) {
    const int row = i >> 7, k = i & 127;
    const float v = (k < WID) ? x0[(size_t)(rbase + row) * WID + k] : 0.0f;
    const _Float16 hi = (_Float16)v;
    const int a = row * KP + (k ^ ((row & 15) << 3));
    xhs[a] = hi;
    xls[a] = (_Float16)(v - (float)hi);
  }

  // output j coordinates: j = j0g[g] + r, 4 groups of 4 consecutive
  int j0g[4];
#pragma unroll
  for (int g = 0; g < 4; ++g) j0g[g] = 32 * ct + 4 * kg + 8 * g;

  // fp32 residual state: 4 x f32x4 (row fixed = row_x)
  f32x4 xres[4];
#pragma unroll
  for (int g = 0; g < 4; ++g) {
    if (j0g[g] <= WID - 4) {
      xres[g] = *(const f32x4*)&x0[(size_t)(rbase + row_x) * WID + j0g[g]];
    } else {
      xres[g] = (f32x4){0.f, 0.f, 0.f, 0.f};
    }
  }
  __syncthreads();

  f32x16 acc;

  // split-f16 GEMM tile: acc += (wh+wl)^T @ (xh+xl), dropping wl*xl
  auto kloop = [&](const int gidx,
                   const _Float16* __restrict__ xhsrc,
                   const _Float16* __restrict__ xlsrc) {
    const _Float16* gh = whi + (size_t)gidx * WCH + ct * 512;
    const _Float16* gl = wlo + (size_t)gidx * WCH + ct * 512;
    f16x8 wh[KS], wl[KS];
#pragma unroll
    for (int ks = 0; ks < KS; ++ks) {       // batch-issue all global loads
      wh[ks] = *(const f16x8*)&gh[ks * 2048 + lane * 8];
      wl[ks] = *(const f16x8*)&gl[ks * 2048 + lane * 8];
    }
#pragma unroll
    for (int ks = 0; ks < KS; ++ks) {
      const int off = row_x * KP + ((16 * ks + 8 * kg) ^ sw);
      const f16x8 xh = *(const f16x8*)&xhsrc[off];
      const f16x8 xl = *(const f16x8*)&xlsrc[off];
      acc = __builtin_amdgcn_mfma_f32_32x32x16_f16(wh[ks], xh, acc, 0, 0, 0);
      acc = __builtin_amdgcn_mfma_f32_32x32x16_f16(wl[ks], xh, acc, 0, 0, 0);
      acc = __builtin_amdgcn_mfma_f32_32x32x16_f16(wh[ks], xl, acc, 0, 0, 0);
    }
  };

  for (int bk = 0; bk < NB; ++bk) {
    // ---------------- GEMM1: v = 2*relu(2*((x+b1)@Wa) + b2) + b3 ----------
#pragma unroll
    for (int e = 0; e < 16; ++e) acc[e] = 0.0f;
    kloop(bk * 2, xhs, xls);
    {
      const float b1 = B1[bk], b2 = B2[bk], b3 = B3[bk];
#pragma unroll
      for (int g = 0; g < 4; ++g) {
        const f32x4 cs = *(const f32x4*)&csA[bk * NP + j0g[g]];
        f16x4 hv, lv;
#pragma unroll
        for (int r = 0; r < 4; ++r) {
          const float t = 2.0f * (acc[g * 4 + r] + b1 * cs[r]) + b2;
          const float v = 2.0f * fmaxf(t, 0.0f) + b3;
          const _Float16 hi = (_Float16)v;
          hv[r] = hi;
          lv[r] = (_Float16)(v - (float)hi);
        }
        const int a = row_x * KP + (j0g[g] ^ sw);
        *(f16x4*)&vhs[a] = hv;
        *(f16x4*)&vls[a] = lv;
      }
    }
    __syncthreads();            // publish v (x-reads of kloop1 also done)

    // ---------------- GEMM2: x = relu(x + (v@Wb)*m + b4) -------------------
#pragma unroll
    for (int e = 0; e < 16; ++e) acc[e] = 0.0f;
    kloop(bk * 2 + 1, vhs, vls);
    {
      const float b4v = B4[bk], mm = M[bk];
#pragma unroll
      for (int g = 0; g < 4; ++g) {
        f16x4 hv, lv;
#pragma unroll
        for (int r = 0; r < 4; ++r) {
          const float xn = fmaxf(xres[g][r] + acc[g * 4 + r] * mm + b4v, 0.0f);
          xres[g][r] = xn;
          const _Float16 hi = (_Float16)xn;
          hv[r] = hi;
          lv[r] = (_Float16)(xn - (float)hi);
        }
        const int a = row_x * KP + (j0g[g] ^ sw);
        *(f16x4*)&xhs[a] = hv;
        *(f16x4*)&xls[a] = lv;
      }
    }
    __syncthreads();            // publish x(bk+1) (v-reads done)
  }

  // write back fp32 residual state
#pragma unroll
  for (int g = 0; g < 4; ++g) {
    if (j0g[g] <= WID - 4)
      *(f32x4*)&x0[(size_t)(rbase + row_x) * WID + j0g[g]] = xres[g];
  }
}

// ---------------------------------------------------------------------------
// Output head + stencil epilogue. One block per batch image (16x16 grid).
// ---------------------------------------------------------------------------
__global__ __launch_bounds__(256) void out_kernel(
    const float* __restrict__ inp, const float* __restrict__ x0,
    const float* __restrict__ Wout, const float* __restrict__ bout,
    float* __restrict__ out) {
  __shared__ float ys[256 * 4];
  __shared__ float wouts[WID * 4];
  __shared__ float bos[4];
  const int tid = threadIdx.x;
  const int b   = blockIdx.x;

  for (int i = tid; i < WID * 4; i += 256) wouts[i] = Wout[i];
  if (tid < 4) bos[tid] = bout[tid];
  __syncthreads();

  const int row = b * 256 + tid;
  const float* xr = x0 + (size_t)row * WID;
  float a0 = 0.f, a1 = 0.f, a2 = 0.f, a3 = 0.f;
#pragma unroll 4
  for (int k = 0; k < WID; ++k) {
    const float xv = xr[k];
    a0 += xv * wouts[k * 4 + 0];
    a1 += xv * wouts[k * 4 + 1];
    a2 += xv * wouts[k * 4 + 2];
    a3 += xv * wouts[k * 4 + 3];
  }
  ys[tid * 4 + 0] = a0 + bos[0];
  ys[tid * 4 + 1] = a1 + bos[1];
  ys[tid * 4 + 2] = a2 + bos[2];
  ys[tid * 4 + 3] = a3 + bos[3];
  __syncthreads();

  const int i = tid >> 4, j = tid & 15;
  const int ip1 = (i + 1) & 15, im1 = (i + 15) & 15;
  const int jp1 = (j + 1) & 15, jm1 = (j + 15) & 15;
  auto Y = [&](int a, int c, int comp) { return ys[(((a << 4) | c) << 2) + comp]; };
  const float y0 = Y(i, j, 0), y1 = Y(i, j, 1), y2 = Y(i, j, 2), y3 = Y(i, j, 3);
  const float right_c = y0 / (Y(ip1, j, 1) + y0);
  const float left_c  = y1 / (y1 + Y(im1, j, 0));
  const float up_c    = y2 / (y2 + Y(i, jp1, 3));
  const float down_c  = y3 / (Y(i, jm1, 2) + y3);

  const float* base = inp + (size_t)b * (32 * 32 * 9);
  const int g1 = 2 * i + 1, g1m = (2 * i + 31) & 31;
  const int g2 = 2 * j + 1, g2m = (2 * j + 31) & 31;
  const float* oo = base + (g1 * 32 + g2) * 9;
  const float* oi = base + (g1 * 32 + g2m) * 9;
  const float* io = base + (g1m * 32 + g2) * 9;
  const float* ii = base + (g1m * 32 + g2m) * 9;
  const float ru = -(oo[0] + oo[3] * right_c + oo[1] * up_c) / oo[4];
  const float rd = -(oi[2] + oi[5] * right_c + oi[1] * down_c) / oi[4];
  const float lu = -(io[6] + io[3] * left_c + io[7] * up_c) / io[4];
  const float ld = -(ii[8] + ii[5] * left_c + ii[7] * down_c) / ii[4];

  float* o = out + (size_t)row * 9;
  o[0] = ld;     o[1] = left_c;  o[2] = lu;
  o[3] = down_c; o[4] = 1.0f;    o[5] = up_c;
  o[6] = rd;     o[7] = right_c; o[8] = ru;
}

// ---------------------------------------------------------------------------
extern "C" void kernel_launch(void* const* d_in, const int* in_sizes, int n_in,
                              void* d_out, int out_size, void* d_ws, size_t ws_size,
                              hipStream_t stream) {
  const float* inp  = (const float*)d_in[0];
  const float* W0   = (const float*)d_in[1];
  const float* Wa   = (const float*)d_in[2];
  const float* Wb   = (const float*)d_in[3];
  const float* B1   = (const float*)d_in[4];
  const float* B2   = (const float*)d_in[5];
  const float* B3   = (const float*)d_in[6];
  const float* B4   = (const float*)d_in[7];
  const float* M    = (const float*)d_in[8];
  const float* Wout = (const float*)d_in[9];
  const float* bout = (const float*)d_in[10];
  float* out = (float*)d_out;

  float* ws     = (float*)d_ws;
  float* x0     = ws;                              // 3,276,800 f32
  _Float16* whi = (_Float16*)(ws + 3276800);       // 100*14336 f16 = 716,800 f32
  _Float16* wlo = (_Float16*)(ws + 3276800 + 716800);
  float* csA    = ws + 3276800 + 716800 + 716800;  // 50*128 f32

  hipLaunchKernelGGL(prep_kernel, dim3(100), dim3(256), 0, stream,
                     Wa, Wb, whi, wlo, csA);
  hipLaunchKernelGGL(first_layer_kernel, dim3(ROWS / 64), dim3(256), 0, stream,
                     inp, W0, x0);
  hipLaunchKernelGGL(chain_kernel, dim3(ROWS / RPW), dim3(512), 0, stream,
                     x0, whi, wlo, csA, B1, B2, B3, B4, M);
  hipLaunchKernelGGL(out_kernel, dim3(BATCH), dim3(256), 0, stream,
                     inp, x0, Wout, bout, out);
}